// Round 6
// baseline (396.262 us; speedup 1.0000x reference)
//
#include <hip/hip_runtime.h>
#include <math.h>

#define N_IMG 4096
#define NBC   1024        // cols per block (256 threads x 4 cols)
#define H_OUT 16          // output rows per block (small => more blocks => TLP)
#define HR    22          // processed rows per block (H_OUT + 6 halo)
#define NBLK_STRIP ((N_IMG/NBC)*(N_IMG/H_OUT))   // 1024
#define NBLK_HIST  2048

struct W7 { float w[7]; };

__device__ __forceinline__ unsigned f2k(float f) {
    unsigned u = __float_as_uint(f);
    return (u & 0x80000000u) ? ~u : (u | 0x80000000u);
}
__device__ __forceinline__ float k2f(unsigned k) {
    unsigned u = (k & 0x80000000u) ? (k & 0x7fffffffu) : ~k;
    return __uint_as_float(u);
}

// Parallel dual-rank select over ghist; runs in the LAST block of the producing
// kernel (ticket pattern). ghist read via atomics (device-coherent, G16).
// state: [0]p1 [1]p2 [2]r1 [3]r2 [4]med [5..7] ticket counters.
__device__ __forceinline__ void dual_select(unsigned* ghist, unsigned* state,
                                            int shift, int per, int last,
                                            unsigned* sscan, unsigned* sres)
{
    const int tid = threadIdx.x;
    unsigned p1 = state[0], p2 = state[1], r1 = state[2], r2 = state[3];
    const bool dual = (p1 != p2);
    for (int q = 0; q < 2; q++) {
        unsigned* h = (q == 1 && dual) ? (ghist + 4096) : ghist;
        const unsigned rank = q ? r2 : r1;
        const int base = tid * per;
        unsigned vals[16];
        unsigned s = 0;
        #pragma unroll
        for (int i = 0; i < 16; i++) {
            vals[i] = (i < per) ? atomicOr(&h[base + i], 0u) : 0u;
            s += vals[i];
        }
        sscan[tid] = s;
        __syncthreads();
        unsigned v = s;
        #pragma unroll
        for (int off = 1; off < 256; off <<= 1) {
            unsigned t = (tid >= off) ? sscan[tid - off] : 0u;
            __syncthreads();
            v += t;
            sscan[tid] = v;
            __syncthreads();
        }
        const unsigned excl = v - s;
        if (rank >= excl && rank < v) {     // unique owner
            unsigned rr = rank - excl;
            unsigned b = (unsigned)base;
            #pragma unroll
            for (int i = 0; i < 16; i++) {
                if (i < per) {
                    unsigned c = vals[i];
                    if (rr < c) { b = (unsigned)(base + i); break; }
                    rr -= c;
                }
            }
            sres[q * 2] = b; sres[q * 2 + 1] = rr;
        }
        __syncthreads();
    }
    if (tid == 0) {
        p1 |= sres[0] << shift;  r1 = sres[1];
        p2 |= sres[2] << shift;  r2 = sres[3];
        state[0] = p1; state[1] = p2; state[2] = r1; state[3] = r2;
        if (last) {
            float a = k2f(p1), b = k2f(p2);
            ((float*)state)[4] = 0.5f * (a + b);
        }
    }
    __syncthreads();
    for (int i = tid; i < 8192; i += 256) ghist[i] = 0;
}

// Register-rolling strip kernel (R4 schedule: load at top, compiler pipelines):
// sobel + products + separable 7x7 gaussian + Harris R + level-0 hist + sel0.
__global__ __launch_bounds__(256) void harris_kernel(const float* __restrict__ x,
                                                     float* __restrict__ R,
                                                     unsigned* __restrict__ ghist,
                                                     unsigned* __restrict__ state,
                                                     W7 wp)
{
    __shared__ unsigned histo[4096];
    __shared__ unsigned sscan[256];
    __shared__ unsigned sres[4];
    __shared__ unsigned lastflag;
    const int tid = threadIdx.x;
    for (int i = tid; i < 4096; i += 256) histo[i] = 0;
    __syncthreads();

    const int row0 = blockIdx.y * H_OUT;
    const int jc   = blockIdx.x * NBC + tid * 4;
    const float* w = wp.w;

    float xm[12], xc[12], xp[12];                  // rolling x rows
    float hxx[7][4], hyy[7][4], hxy[7][4];         // 7-deep ring of h rows

    auto loadrow = [&](int ri, float* d) {
        if ((unsigned)ri < N_IMG) {
            const float* p = x + (size_t)ri * N_IMG;
            float4 v0 = make_float4(0.f,0.f,0.f,0.f), v2 = make_float4(0.f,0.f,0.f,0.f);
            if (jc >= 4) v0 = *(const float4*)(p + jc - 4);
            float4 v1 = *(const float4*)(p + jc);
            if (jc + 4 < N_IMG) v2 = *(const float4*)(p + jc + 4);
            d[0]=v0.x; d[1]=v0.y; d[2]=v0.z; d[3]=v0.w;
            d[4]=v1.x; d[5]=v1.y; d[6]=v1.z; d[7]=v1.w;
            d[8]=v2.x; d[9]=v2.y; d[10]=v2.z; d[11]=v2.w;
        } else {
            #pragma unroll
            for (int t = 0; t < 12; t++) d[t] = 0.f;
        }
    };

    loadrow(row0 - 4, xm);
    loadrow(row0 - 3, xc);

    int curb = -1; unsigned cnt = 0;   // histogram run-length state

    for (int it = 0; it < 4; ++it) {
        #pragma unroll
        for (int k = 0; k < 7; ++k) {
            const int r = it * 7 + k;          // ring slot == k (r mod 7)
            if (r < HR) {
                const int ri = row0 + r - 3;   // image row of this h row
                loadrow(ri + 1, xp);

                float sxx[4] = {0,0,0,0}, syy[4] = {0,0,0,0}, sxy[4] = {0,0,0,0};
                if ((unsigned)ri < N_IMG) {
                    float dc[12], rd[12];
                    #pragma unroll
                    for (int t = 0; t < 12; t++) {
                        dc[t] = xm[t] + 2.f * xc[t] + xp[t];
                        rd[t] = xp[t] - xm[t];
                    }
                    #pragma unroll
                    for (int t = 0; t < 10; t++) {
                        float ix = dc[t+2] - dc[t];
                        float iy = rd[t] + 2.f * rd[t+1] + rd[t+2];
                        if ((unsigned)(jc - 3 + t) >= N_IMG) { ix = 0.f; iy = 0.f; }
                        float xx = ix*ix, yy = iy*iy, xy = ix*iy;
                        #pragma unroll
                        for (int o = 0; o < 4; o++) {
                            int v = t - o;
                            if (v >= 0 && v < 7) {
                                sxx[o] = fmaf(w[v], xx, sxx[o]);
                                syy[o] = fmaf(w[v], yy, syy[o]);
                                sxy[o] = fmaf(w[v], xy, sxy[o]);
                            }
                        }
                    }
                }
                #pragma unroll
                for (int o = 0; o < 4; o++) {
                    hxx[k][o] = sxx[o]; hyy[k][o] = syy[o]; hxy[k][o] = sxy[o];
                }

                if (r >= 6) {
                    float4 h;
                    float* hp = &h.x;
                    #pragma unroll
                    for (int o = 0; o < 4; o++) {
                        float ax = 0.f, ay = 0.f, az = 0.f;
                        #pragma unroll
                        for (int u = 0; u < 7; u++) {
                            const int s = (k + 1 + u) % 7;   // static
                            ax = fmaf(w[u], hxx[s][o], ax);
                            ay = fmaf(w[u], hyy[s][o], ay);
                            az = fmaf(w[u], hxy[s][o], az);
                        }
                        float tr = ax + ay;
                        hp[o] = ax*ay - az*az - 0.05f*tr*tr;
                    }
                    const int orow = row0 + r - 6;
                    *(float4*)(R + (size_t)orow * N_IMG + jc) = h;
                    #pragma unroll
                    for (int o = 0; o < 4; o++) {
                        int b = (int)(f2k(hp[o]) >> 20);
                        if (b == curb) cnt++;
                        else { if (curb >= 0) atomicAdd(&histo[curb], cnt); curb = b; cnt = 1; }
                    }
                }
                #pragma unroll
                for (int t = 0; t < 12; t++) { xm[t] = xc[t]; xc[t] = xp[t]; }
            }
        }
    }
    if (curb >= 0) atomicAdd(&histo[curb], cnt);
    __syncthreads();
    for (int i = tid; i < 4096; i += 256) {
        unsigned c = histo[i];
        if (c) atomicAdd(&ghist[i], c);
    }
    __syncthreads();

    // ---- last block runs select level 0 (bits [31:20], per=16) ----
    if (tid == 0) {
        __threadfence();
        unsigned t = atomicAdd(&state[5], 1u);
        lastflag = (t == NBLK_STRIP - 1) ? 1u : 0u;
    }
    __syncthreads();
    if (lastflag) dual_select(ghist, state, 20, 16, 0, sscan, sres);
}

// dual-rank radix-select histogram pass + fused select (last block)
__global__ __launch_bounds__(256) void hist_kernel(const float* __restrict__ R,
                                                   unsigned* __restrict__ ghist,
                                                   unsigned* __restrict__ state,
                                                   unsigned mask, int shift, int per,
                                                   int last, int cslot)
{
    __shared__ unsigned h[2][4096];
    __shared__ unsigned sscan[256];
    __shared__ unsigned sres[4];
    __shared__ unsigned lastflag;
    const int tid = threadIdx.x;
    const int bins = per << 8;
    for (int i = tid; i < 8192; i += 256) ((unsigned*)h)[i] = 0;
    __syncthreads();
    const unsigned p1 = state[0], p2 = state[1];
    const bool dual = (p1 != p2);
    const int n4 = (N_IMG * N_IMG) / 4;
    int curb1 = -1; unsigned cnt1 = 0;
    int curb2 = -1; unsigned cnt2 = 0;
    const float4* R4 = (const float4*)R;
    for (int i = blockIdx.x * 256 + tid; i < n4; i += gridDim.x * 256) {
        float4 v = R4[i];
        float vv[4] = {v.x, v.y, v.z, v.w};
        #pragma unroll
        for (int t = 0; t < 4; t++) {
            unsigned k = f2k(vv[t]);
            if ((k & mask) == p1) {
                int b = (int)((k >> shift) & (unsigned)(bins - 1));
                if (b == curb1) cnt1++;
                else { if (cnt1) atomicAdd(&h[0][curb1], cnt1); curb1 = b; cnt1 = 1; }
            }
            if (dual && (k & mask) == p2) {
                int b = (int)((k >> shift) & (unsigned)(bins - 1));
                if (b == curb2) cnt2++;
                else { if (cnt2) atomicAdd(&h[1][curb2], cnt2); curb2 = b; cnt2 = 1; }
            }
        }
    }
    if (cnt1) atomicAdd(&h[0][curb1], cnt1);
    if (cnt2) atomicAdd(&h[1][curb2], cnt2);
    __syncthreads();
    for (int i = tid; i < bins; i += 256) {
        unsigned c0 = h[0][i]; if (c0) atomicAdd(&ghist[i], c0);
        if (dual) { unsigned c1 = h[1][i]; if (c1) atomicAdd(&ghist[4096 + i], c1); }
    }
    __syncthreads();

    if (tid == 0) {
        __threadfence();
        unsigned t = atomicAdd(&state[cslot], 1u);
        lastflag = (t == NBLK_HIST - 1) ? 1u : 0u;
    }
    __syncthreads();
    if (lastflag) dual_select(ghist, state, shift, per, last, sscan, sres);
}

__global__ __launch_bounds__(256) void init_kernel(unsigned* __restrict__ ghist,
                                                   unsigned* __restrict__ state)
{
    const int tid = threadIdx.x;
    for (int i = tid; i < 8192; i += 256) ghist[i] = 0;
    if (tid == 0) {
        state[0] = 0u; state[1] = 0u;
        state[2] = 8388607u;   // N/2 - 1
        state[3] = 8388608u;   // N/2
        state[4] = 0u;
        state[5] = 0u; state[6] = 0u; state[7] = 0u;   // ticket counters
    }
}

// Register-rolling NMS (R4 schedule): threshold + separable 7x7 max. No LDS.
__global__ __launch_bounds__(256) void nms_kernel(const float* __restrict__ R,
                                                  const unsigned* __restrict__ state,
                                                  float* __restrict__ out)
{
    const int tid  = threadIdx.x;
    const int row0 = blockIdx.y * H_OUT;
    const int jc   = blockIdx.x * NBC + tid * 4;
    const float med = ((const float*)state)[4];

    float hm[7][4], ct[7][4];

    for (int it = 0; it < 4; ++it) {
        #pragma unroll
        for (int k = 0; k < 7; ++k) {
            const int r = it * 7 + k;
            if (r < HR) {
                const int ri = row0 + r - 3;
                float a[12];
                if ((unsigned)ri < N_IMG) {
                    const float* p = R + (size_t)ri * N_IMG;
                    float4 v1 = *(const float4*)(p + jc);
                    a[4] = (v1.x >= med) ? v1.x : 0.f;
                    a[5] = (v1.y >= med) ? v1.y : 0.f;
                    a[6] = (v1.z >= med) ? v1.z : 0.f;
                    a[7] = (v1.w >= med) ? v1.w : 0.f;
                    if (jc >= 4) {
                        float4 v0 = *(const float4*)(p + jc - 4);
                        a[0] = (v0.x >= med) ? v0.x : 0.f;
                        a[1] = (v0.y >= med) ? v0.y : 0.f;
                        a[2] = (v0.z >= med) ? v0.z : 0.f;
                        a[3] = (v0.w >= med) ? v0.w : 0.f;
                    } else { a[0]=a[1]=a[2]=a[3] = -INFINITY; }
                    if (jc + 4 < N_IMG) {
                        float4 v2 = *(const float4*)(p + jc + 4);
                        a[8]  = (v2.x >= med) ? v2.x : 0.f;
                        a[9]  = (v2.y >= med) ? v2.y : 0.f;
                        a[10] = (v2.z >= med) ? v2.z : 0.f;
                        a[11] = (v2.w >= med) ? v2.w : 0.f;
                    } else { a[8]=a[9]=a[10]=a[11] = -INFINITY; }
                } else {
                    #pragma unroll
                    for (int t = 0; t < 12; t++) a[t] = -INFINITY;
                }
                #pragma unroll
                for (int o = 0; o < 4; o++) {
                    float m = a[o+1];
                    #pragma unroll
                    for (int t = 2; t <= 7; t++) m = fmaxf(m, a[o+t]);
                    hm[k][o] = m;
                    ct[k][o] = a[4+o];
                }
                if (r >= 6) {
                    float4 ov;
                    float* op = &ov.x;
                    #pragma unroll
                    for (int o = 0; o < 4; o++) {
                        float m = hm[(k+1) % 7][o];
                        #pragma unroll
                        for (int u = 1; u < 7; u++) m = fmaxf(m, hm[(k+1+u) % 7][o]);
                        float c = ct[(k+4) % 7][o];
                        op[o] = (c != m) ? 0.f : m;
                    }
                    const int orow = row0 + r - 6;
                    *(float4*)(out + (size_t)orow * N_IMG + jc) = ov;
                }
            }
        }
    }
}

extern "C" void kernel_launch(void* const* d_in, const int* in_sizes, int n_in,
                              void* d_out, int out_size, void* d_ws, size_t ws_size,
                              hipStream_t stream)
{
    const float* x = (const float*)d_in[0];
    float* R = (float*)d_ws;                                   // 64 MB
    unsigned* ghist = (unsigned*)((char*)d_ws + (size_t)N_IMG * N_IMG * 4);
    unsigned* state = ghist + 8192;
    float* out = (float*)d_out;

    W7 wp;
    {
        double g[7], s = 0.0;
        for (int i = 0; i < 7; i++) { double ax = (double)i - 3.0; g[i] = exp(-(ax*ax)/50.0); s += g[i]; }
        for (int i = 0; i < 7; i++) wp.w[i] = (float)(g[i] / s);
    }

    dim3 sgrid(N_IMG / NBC, N_IMG / H_OUT);   // (4, 256) = 1024 blocks

    init_kernel<<<1, 256, 0, stream>>>(ghist, state);
    harris_kernel<<<sgrid, 256, 0, stream>>>(x, R, ghist, state, wp);      // + hist0 + sel0
    hist_kernel<<<NBLK_HIST, 256, 0, stream>>>(R, ghist, state, 0xFFF00000u, 8, 16, 0, 6);  // + sel1
    hist_kernel<<<NBLK_HIST, 256, 0, stream>>>(R, ghist, state, 0xFFFFFF00u, 0, 1, 1, 7);   // + sel2 + med
    nms_kernel<<<sgrid, 256, 0, stream>>>(R, state, out);
}

// Round 7
// 334.506 us; speedup vs baseline: 1.1846x; 1.1846x over previous
//
#include <hip/hip_runtime.h>
#include <math.h>

#define N_IMG 4096
#define NBC   1024        // cols per block (256 threads x 4 cols)
#define H_OUT 32          // output rows per block (R4-proven geometry)
#define HR    38          // processed rows per block (H_OUT + 6 halo)
#define NBLK_HIST 2048
#define STAGE_CAP 4096    // LDS record staging (16 KB)

struct W7 { float w[7]; };

__device__ __forceinline__ unsigned f2k(float f) {
    unsigned u = __float_as_uint(f);
    return (u & 0x80000000u) ? ~u : (u | 0x80000000u);
}
__device__ __forceinline__ float k2f(unsigned k) {
    unsigned u = (k & 0x80000000u) ? (k & 0x7fffffffu) : ~k;
    return __uint_as_float(u);
}

// ============ harris: EXACT R4 structure (register-rolling strip) ============
__global__ __launch_bounds__(256) void harris_kernel(const float* __restrict__ x,
                                                     float* __restrict__ R,
                                                     unsigned* __restrict__ ghist,
                                                     W7 wp)
{
    __shared__ unsigned histo[4096];
    const int tid = threadIdx.x;
    for (int i = tid; i < 4096; i += 256) histo[i] = 0;
    __syncthreads();

    const int row0 = blockIdx.y * H_OUT;
    const int jc   = blockIdx.x * NBC + tid * 4;
    const float* w = wp.w;

    float xm[12], xc[12], xp[12];
    float hxx[7][4], hyy[7][4], hxy[7][4];

    auto loadrow = [&](int ri, float* d) {
        if ((unsigned)ri < N_IMG) {
            const float* p = x + (size_t)ri * N_IMG;
            float4 v0 = make_float4(0.f,0.f,0.f,0.f), v2 = make_float4(0.f,0.f,0.f,0.f);
            if (jc >= 4) v0 = *(const float4*)(p + jc - 4);
            float4 v1 = *(const float4*)(p + jc);
            if (jc + 4 < N_IMG) v2 = *(const float4*)(p + jc + 4);
            d[0]=v0.x; d[1]=v0.y; d[2]=v0.z; d[3]=v0.w;
            d[4]=v1.x; d[5]=v1.y; d[6]=v1.z; d[7]=v1.w;
            d[8]=v2.x; d[9]=v2.y; d[10]=v2.z; d[11]=v2.w;
        } else {
            #pragma unroll
            for (int t = 0; t < 12; t++) d[t] = 0.f;
        }
    };

    loadrow(row0 - 4, xm);
    loadrow(row0 - 3, xc);

    int curb = -1; unsigned cnt = 0;

    for (int it = 0; it < 6; ++it) {
        #pragma unroll
        for (int k = 0; k < 7; ++k) {
            const int r = it * 7 + k;
            if (r < HR) {
                const int ri = row0 + r - 3;
                loadrow(ri + 1, xp);

                float sxx[4] = {0,0,0,0}, syy[4] = {0,0,0,0}, sxy[4] = {0,0,0,0};
                if ((unsigned)ri < N_IMG) {
                    float dc[12], rd[12];
                    #pragma unroll
                    for (int t = 0; t < 12; t++) {
                        dc[t] = xm[t] + 2.f * xc[t] + xp[t];
                        rd[t] = xp[t] - xm[t];
                    }
                    #pragma unroll
                    for (int t = 0; t < 10; t++) {
                        float ix = dc[t+2] - dc[t];
                        float iy = rd[t] + 2.f * rd[t+1] + rd[t+2];
                        if ((unsigned)(jc - 3 + t) >= N_IMG) { ix = 0.f; iy = 0.f; }
                        float xx = ix*ix, yy = iy*iy, xy = ix*iy;
                        #pragma unroll
                        for (int o = 0; o < 4; o++) {
                            int v = t - o;
                            if (v >= 0 && v < 7) {
                                sxx[o] = fmaf(w[v], xx, sxx[o]);
                                syy[o] = fmaf(w[v], yy, syy[o]);
                                sxy[o] = fmaf(w[v], xy, sxy[o]);
                            }
                        }
                    }
                }
                #pragma unroll
                for (int o = 0; o < 4; o++) {
                    hxx[k][o] = sxx[o]; hyy[k][o] = syy[o]; hxy[k][o] = sxy[o];
                }

                if (r >= 6) {
                    float4 h;
                    float* hp = &h.x;
                    #pragma unroll
                    for (int o = 0; o < 4; o++) {
                        float ax = 0.f, ay = 0.f, az = 0.f;
                        #pragma unroll
                        for (int u = 0; u < 7; u++) {
                            const int s = (k + 1 + u) % 7;
                            ax = fmaf(w[u], hxx[s][o], ax);
                            ay = fmaf(w[u], hyy[s][o], ay);
                            az = fmaf(w[u], hxy[s][o], az);
                        }
                        float tr = ax + ay;
                        hp[o] = ax*ay - az*az - 0.05f*tr*tr;
                    }
                    const int orow = row0 + r - 6;
                    *(float4*)(R + (size_t)orow * N_IMG + jc) = h;
                    #pragma unroll
                    for (int o = 0; o < 4; o++) {
                        int b = (int)(f2k(hp[o]) >> 20);
                        if (b == curb) cnt++;
                        else { if (curb >= 0) atomicAdd(&histo[curb], cnt); curb = b; cnt = 1; }
                    }
                }
                #pragma unroll
                for (int t = 0; t < 12; t++) { xm[t] = xc[t]; xc[t] = xp[t]; }
            }
        }
    }
    if (curb >= 0) atomicAdd(&histo[curb], cnt);
    __syncthreads();
    for (int i = tid; i < 4096; i += 256) {
        unsigned c = histo[i];
        if (c) atomicAdd(&ghist[i], c);
    }
}

// ============ standalone parallel dual-rank select (R2-proven) ============
__global__ __launch_bounds__(256) void select_kernel(unsigned* __restrict__ ghist,
                                                     unsigned* __restrict__ state,
                                                     int shift, int bins, int last)
{
    __shared__ unsigned scan[256];
    __shared__ unsigned res_b[2], res_r[2];
    const int tid = threadIdx.x;
    const int per = bins >> 8;
    unsigned p1 = state[0], p2 = state[1];
    unsigned r1 = state[2], r2 = state[3];
    const bool dual = (p1 != p2);

    for (int q = 0; q < 2; q++) {
        const unsigned* h = (q == 1 && dual) ? (ghist + 4096) : ghist;
        const unsigned rank = (q == 0) ? r1 : r2;
        const int base = tid * per;
        unsigned s = 0;
        for (int i = 0; i < per; i++) s += h[base + i];
        scan[tid] = s;
        __syncthreads();
        unsigned v = s;
        #pragma unroll
        for (int off = 1; off < 256; off <<= 1) {
            unsigned t = (tid >= off) ? scan[tid - off] : 0u;
            __syncthreads();
            v += t;
            scan[tid] = v;
            __syncthreads();
        }
        const unsigned excl = v - s;
        if (rank >= excl && rank < v) {
            unsigned rr = rank - excl;
            unsigned b = (unsigned)base;
            for (int i = 0; i < per; i++) {
                unsigned c = h[base + i];
                if (rr < c) { b = (unsigned)(base + i); break; }
                rr -= c;
            }
            res_b[q] = b; res_r[q] = rr;
        }
        __syncthreads();
    }
    if (tid == 0) {
        p1 |= res_b[0] << shift;  r1 = res_r[0];
        p2 |= res_b[1] << shift;  r2 = res_r[1];
        state[0] = p1; state[1] = p2; state[2] = r1; state[3] = r2;
        if (last) {
            float a = k2f(p1), b = k2f(p2);
            ((float*)state)[4] = 0.5f * (a + b);
        }
    }
    __syncthreads();
    for (int i = tid; i < 8192; i += 256) ghist[i] = 0;
}

// ============ level-1 hist (bits [19:8]) + candidate recording ============
// Matching keys (12-bit prefix p1 or p2) are exactly the level-2 candidates:
// stage them in LDS, flush to a global record buffer. Overflow -> state[7]=1.
__global__ __launch_bounds__(256) void hist1rec_kernel(const float* __restrict__ R,
                                                       unsigned* __restrict__ ghist,
                                                       unsigned* __restrict__ state,
                                                       unsigned* __restrict__ rec,
                                                       unsigned reccap)
{
    __shared__ unsigned h[2][4096];      // 32 KB
    __shared__ unsigned stage[STAGE_CAP];// 16 KB
    __shared__ unsigned scount, sbase, soflow;
    const int tid = threadIdx.x;
    for (int i = tid; i < 8192; i += 256) ((unsigned*)h)[i] = 0;
    if (tid == 0) { scount = 0; soflow = 0; }
    __syncthreads();

    const unsigned p1 = state[0], p2 = state[1];
    const bool dual = (p1 != p2);
    int curb1 = -1; unsigned cnt1 = 0;
    int curb2 = -1; unsigned cnt2 = 0;
    const float4* R4 = (const float4*)R;
    const int n4 = (N_IMG * N_IMG) / 4;          // 4194304
    const int stride = NBLK_HIST * 256;          // 524288 -> exactly 8 iters

    for (int ii = 0; ii < n4 / stride; ii++) {
        int i = blockIdx.x * 256 + tid + ii * stride;
        float4 v = R4[i];
        float vv[4] = {v.x, v.y, v.z, v.w};
        #pragma unroll
        for (int t = 0; t < 4; t++) {
            unsigned k = f2k(vv[t]);
            bool m1 = ((k & 0xFFF00000u) == p1);
            bool m2 = dual && ((k & 0xFFF00000u) == p2);
            if (m1) {
                int b = (int)((k >> 8) & 4095u);
                if (b == curb1) cnt1++;
                else { if (cnt1) atomicAdd(&h[0][curb1], cnt1); curb1 = b; cnt1 = 1; }
            }
            if (m2) {
                int b = (int)((k >> 8) & 4095u);
                if (b == curb2) cnt2++;
                else { if (cnt2) atomicAdd(&h[1][curb2], cnt2); curb2 = b; cnt2 = 1; }
            }
            if (m1 || m2) {
                unsigned s = atomicAdd(&scount, 1u);
                if (s < STAGE_CAP) stage[s] = k;
                else soflow = 1u;
            }
        }
        // flush staging if it could overflow next iteration (max +1024)
        __syncthreads();
        if (scount > STAGE_CAP - 1024) {
            if (tid == 0) sbase = atomicAdd(&state[6], scount);
            __syncthreads();
            unsigned n = (scount < STAGE_CAP) ? scount : STAGE_CAP;
            for (unsigned j = tid; j < n; j += 256) {
                unsigned gi = sbase + j;
                if (gi < reccap) rec[gi] = stage[j];
                else soflow = 1u;
            }
            __syncthreads();
            if (tid == 0) scount = 0;
            __syncthreads();
        }
    }
    // final flush
    __syncthreads();
    if (scount > 0) {
        if (tid == 0) sbase = atomicAdd(&state[6], scount);
        __syncthreads();
        unsigned n = (scount < STAGE_CAP) ? scount : STAGE_CAP;
        for (unsigned j = tid; j < n; j += 256) {
            unsigned gi = sbase + j;
            if (gi < reccap) rec[gi] = stage[j];
            else soflow = 1u;
        }
        __syncthreads();
    }
    if (cnt1) atomicAdd(&h[0][curb1], cnt1);
    if (cnt2) atomicAdd(&h[1][curb2], cnt2);
    if (tid == 0 && soflow) atomicOr(&state[7], 1u);
    __syncthreads();
    for (int i = tid; i < 4096; i += 256) {
        unsigned c0 = h[0][i]; if (c0) atomicAdd(&ghist[i], c0);
        if (dual) { unsigned c1 = h[1][i]; if (c1) atomicAdd(&ghist[4096 + i], c1); }
    }
}

// ============ final level (bits [7:0]) from records + fused select ============
__global__ __launch_bounds__(256) void selfinal_kernel(const float* __restrict__ R,
                                                       unsigned* __restrict__ ghist,
                                                       unsigned* __restrict__ state,
                                                       const unsigned* __restrict__ rec)
{
    __shared__ unsigned h0[256], h1[256];
    __shared__ unsigned sscan[256];
    __shared__ unsigned sres[4];
    __shared__ unsigned lastflag;
    const int tid = threadIdx.x;
    h0[tid] = 0; h1[tid] = 0;
    __syncthreads();

    const unsigned p1 = state[0], p2 = state[1];      // 24-bit prefixes
    const bool dual = (p1 != p2);
    const unsigned oflow = state[7];

    if (!oflow) {
        const unsigned n = state[6];
        for (unsigned i = blockIdx.x * 256 + tid; i < n; i += NBLK_HIST * 256) {
            unsigned k = rec[i];
            unsigned pre = k & 0xFFFFFF00u;
            if (pre == p1) atomicAdd(&h0[k & 255u], 1u);
            else if (dual && pre == p2) atomicAdd(&h1[k & 255u], 1u);
        }
    } else {
        // fallback: full scan of R (records incomplete)
        const float4* R4 = (const float4*)R;
        const int n4 = (N_IMG * N_IMG) / 4;
        for (int i = blockIdx.x * 256 + tid; i < n4; i += NBLK_HIST * 256) {
            float4 v = R4[i];
            float vv[4] = {v.x, v.y, v.z, v.w};
            #pragma unroll
            for (int t = 0; t < 4; t++) {
                unsigned k = f2k(vv[t]);
                unsigned pre = k & 0xFFFFFF00u;
                if (pre == p1) atomicAdd(&h0[k & 255u], 1u);
                else if (dual && pre == p2) atomicAdd(&h1[k & 255u], 1u);
            }
        }
    }
    __syncthreads();
    { unsigned c = h0[tid]; if (c) atomicAdd(&ghist[tid], c); }
    if (dual) { unsigned c = h1[tid]; if (c) atomicAdd(&ghist[4096 + tid], c); }
    __syncthreads();

    if (tid == 0) {
        __threadfence();
        unsigned t = atomicAdd(&state[5], 1u);
        lastflag = (t == NBLK_HIST - 1) ? 1u : 0u;
    }
    __syncthreads();
    if (!lastflag) return;

    // ---- last block: select over 256 bins (dual-rank), write median ----
    unsigned q1 = state[0], q2 = state[1], r1 = state[2], r2 = state[3];
    for (int q = 0; q < 2; q++) {
        unsigned* hh = (q == 1 && dual) ? (ghist + 4096) : ghist;
        const unsigned rank = q ? r2 : r1;
        unsigned s = atomicOr(&hh[tid], 0u);
        sscan[tid] = s;
        __syncthreads();
        unsigned v = s;
        #pragma unroll
        for (int off = 1; off < 256; off <<= 1) {
            unsigned t = (tid >= off) ? sscan[tid - off] : 0u;
            __syncthreads();
            v += t;
            sscan[tid] = v;
            __syncthreads();
        }
        const unsigned excl = v - s;
        if (rank >= excl && rank < v) { sres[q * 2] = (unsigned)tid; sres[q * 2 + 1] = rank - excl; }
        __syncthreads();
    }
    if (tid == 0) {
        q1 |= sres[0];  q2 |= sres[2];
        state[0] = q1; state[1] = q2; state[2] = sres[1]; state[3] = sres[3];
        float a = k2f(q1), b = k2f(q2);
        ((float*)state)[4] = 0.5f * (a + b);
    }
}

__global__ __launch_bounds__(256) void init_kernel(unsigned* __restrict__ ghist,
                                                   unsigned* __restrict__ state)
{
    const int tid = threadIdx.x;
    for (int i = tid; i < 8192; i += 256) ghist[i] = 0;
    if (tid == 0) {
        state[0] = 0u; state[1] = 0u;
        state[2] = 8388607u;   // N/2 - 1
        state[3] = 8388608u;   // N/2
        state[4] = 0u;
        state[5] = 0u;         // selfinal ticket
        state[6] = 0u;         // record count
        state[7] = 0u;         // overflow flag
    }
}

// ============ nms: EXACT R4 structure ============
__global__ __launch_bounds__(256) void nms_kernel(const float* __restrict__ R,
                                                  const unsigned* __restrict__ state,
                                                  float* __restrict__ out)
{
    const int tid  = threadIdx.x;
    const int row0 = blockIdx.y * H_OUT;
    const int jc   = blockIdx.x * NBC + tid * 4;
    const float med = ((const float*)state)[4];

    float hm[7][4], ct[7][4];

    for (int it = 0; it < 6; ++it) {
        #pragma unroll
        for (int k = 0; k < 7; ++k) {
            const int r = it * 7 + k;
            if (r < HR) {
                const int ri = row0 + r - 3;
                float a[12];
                if ((unsigned)ri < N_IMG) {
                    const float* p = R + (size_t)ri * N_IMG;
                    float4 v1 = *(const float4*)(p + jc);
                    a[4] = (v1.x >= med) ? v1.x : 0.f;
                    a[5] = (v1.y >= med) ? v1.y : 0.f;
                    a[6] = (v1.z >= med) ? v1.z : 0.f;
                    a[7] = (v1.w >= med) ? v1.w : 0.f;
                    if (jc >= 4) {
                        float4 v0 = *(const float4*)(p + jc - 4);
                        a[0] = (v0.x >= med) ? v0.x : 0.f;
                        a[1] = (v0.y >= med) ? v0.y : 0.f;
                        a[2] = (v0.z >= med) ? v0.z : 0.f;
                        a[3] = (v0.w >= med) ? v0.w : 0.f;
                    } else { a[0]=a[1]=a[2]=a[3] = -INFINITY; }
                    if (jc + 4 < N_IMG) {
                        float4 v2 = *(const float4*)(p + jc + 4);
                        a[8]  = (v2.x >= med) ? v2.x : 0.f;
                        a[9]  = (v2.y >= med) ? v2.y : 0.f;
                        a[10] = (v2.z >= med) ? v2.z : 0.f;
                        a[11] = (v2.w >= med) ? v2.w : 0.f;
                    } else { a[8]=a[9]=a[10]=a[11] = -INFINITY; }
                } else {
                    #pragma unroll
                    for (int t = 0; t < 12; t++) a[t] = -INFINITY;
                }
                #pragma unroll
                for (int o = 0; o < 4; o++) {
                    float m = a[o+1];
                    #pragma unroll
                    for (int t = 2; t <= 7; t++) m = fmaxf(m, a[o+t]);
                    hm[k][o] = m;
                    ct[k][o] = a[4+o];
                }
                if (r >= 6) {
                    float4 ov;
                    float* op = &ov.x;
                    #pragma unroll
                    for (int o = 0; o < 4; o++) {
                        float m = hm[(k+1) % 7][o];
                        #pragma unroll
                        for (int u = 1; u < 7; u++) m = fmaxf(m, hm[(k+1+u) % 7][o]);
                        float c = ct[(k+4) % 7][o];
                        op[o] = (c != m) ? 0.f : m;
                    }
                    const int orow = row0 + r - 6;
                    *(float4*)(out + (size_t)orow * N_IMG + jc) = ov;
                }
            }
        }
    }
}

extern "C" void kernel_launch(void* const* d_in, const int* in_sizes, int n_in,
                              void* d_out, int out_size, void* d_ws, size_t ws_size,
                              hipStream_t stream)
{
    const float* x = (const float*)d_in[0];
    const size_t R_BYTES = (size_t)N_IMG * N_IMG * 4;          // 64 MB
    float* R = (float*)d_ws;
    unsigned* ghist = (unsigned*)((char*)d_ws + R_BYTES);      // 32 KB
    unsigned* state = ghist + 8192;                            // 8 uints
    const size_t recOff = R_BYTES + 40960;                     // 64 MB + 40 KB
    unsigned* rec = (unsigned*)((char*)d_ws + recOff);
    unsigned reccap = 0;
    if (ws_size > recOff + 4) {
        size_t c = (ws_size - recOff) / 4;
        reccap = (c > 8u * 1024 * 1024) ? 8u * 1024 * 1024 : (unsigned)c;
    }
    float* out = (float*)d_out;

    W7 wp;
    {
        double g[7], s = 0.0;
        for (int i = 0; i < 7; i++) { double ax = (double)i - 3.0; g[i] = exp(-(ax*ax)/50.0); s += g[i]; }
        for (int i = 0; i < 7; i++) wp.w[i] = (float)(g[i] / s);
    }

    dim3 sgrid(N_IMG / NBC, N_IMG / H_OUT);   // (4, 128)

    init_kernel<<<1, 256, 0, stream>>>(ghist, state);
    harris_kernel<<<sgrid, 256, 0, stream>>>(x, R, ghist, wp);
    select_kernel<<<1, 256, 0, stream>>>(ghist, state, 20, 4096, 0);            // 12-bit prefixes
    hist1rec_kernel<<<NBLK_HIST, 256, 0, stream>>>(R, ghist, state, rec, reccap);
    select_kernel<<<1, 256, 0, stream>>>(ghist, state, 8, 4096, 0);             // 24-bit prefixes
    selfinal_kernel<<<NBLK_HIST, 256, 0, stream>>>(R, ghist, state, rec);       // median
    nms_kernel<<<sgrid, 256, 0, stream>>>(R, state, out);
}